// Round 1
// baseline (12076.091 us; speedup 1.0000x reference)
//
#include <hip/hip_runtime.h>

// Fused 64-layer GRU, H=64, T=2, B=16384 (only upper half of batch feeds the
// output -- reference's reshape(T,B,-1)[-1] selects rows b = B/2 + b'//2,
// t = b'%2).
//
// Layout: 128 blocks x 512 threads. Block = 64 batch rows; 8 waves per block
// each own 8 output elements j (lanes = rows -> weight addresses are
// wave-uniform -> s_load + SGPR-operand FMA). h exchanged across j-waves via
// LDS, 2 barriers/layer. Per layer: phase A computes t=0 hidden state (h=0 so
// gh=bh) plus the t=1 input gates (Wi rows reused for both timesteps); phase B
// does the t=1 hidden GEMM + gates.

namespace {

constexpr int kH    = 64;          // hidden size
constexpr int kL    = 64;          // layers
constexpr int kB    = 16384;       // batch
constexpr int kRows = kB / 2;      // rows that matter: 8192..16383
constexpr int kRPB  = 64;          // rows per block (one wave of rows)
constexpr int kJW   = 8;           // j-split waves per block
constexpr int kJPT  = kH / kJW;    // j per thread = 8
constexpr int kBlk  = kJW * 64;    // 512 threads

__device__ __forceinline__ float sigm(float v) {
    float e = __expf(-v);
    return __builtin_amdgcn_rcpf(1.0f + e);
}
// tanh(x) = (1 - e^-2x) / (1 + e^-2x); |x| < ~20 here so no overflow.
__device__ __forceinline__ float tanh_fast(float v) {
    float e = __expf(-2.0f * v);
    return (1.0f - e) * __builtin_amdgcn_rcpf(1.0f + e);
}

} // namespace

extern "C" __global__ __launch_bounds__(kBlk, 2)
void gru_fused(const float* __restrict__ x,
               const float* __restrict__ Wih0, const float* __restrict__ Whh0,
               const float* __restrict__ bih0, const float* __restrict__ bhh0,
               const float* __restrict__ WihL, const float* __restrict__ WhhL,
               const float* __restrict__ bihL, const float* __restrict__ bhhL,
               const float* __restrict__ Wf,   const float* __restrict__ bfp,
               float* __restrict__ out)
{
    __shared__ float h0buf[kH][kRPB];      // [j][row] 16 KiB
    __shared__ float h1buf[kH][kRPB];      // 16 KiB
    __shared__ float i1buf[3][kH][kRPB];   // t=1 input gates (r,z,n) 48 KiB

    const int tid  = (int)threadIdx.x;
    const int lane = tid & 63;                                   // row in block
    const int jw   = __builtin_amdgcn_readfirstlane(tid >> 6);   // 0..7
    const int grow = kB / 2 + (int)blockIdx.x * kRPB + lane;     // global row

    float x0[kH], x1[kH];            // this row's layer input, t=0 / t=1
    const float xv0 = x[grow * 2 + 0];
    const float xv1 = x[grow * 2 + 1];

    for (int l = 0; l < kL; ++l) {
        const float *Wi, *Wh, *bi, *bh;
        if (l == 0) { Wi = Wih0; Wh = Whh0; bi = bih0; bh = bhh0; }
        else {
            Wi = WihL + (size_t)(l - 1) * 3 * kH * kH;
            Wh = WhhL + (size_t)(l - 1) * 3 * kH * kH;
            bi = bihL + (size_t)(l - 1) * 3 * kH;
            bh = bhhL + (size_t)(l - 1) * 3 * kH;
        }

        // ---- phase A: t=0 output + t=1 input gates ----
        #pragma unroll 1
        for (int jj = 0; jj < kJPT; ++jj) {
            const int j = jw * kJPT + jj;
            float ar0, az0, an0, ar1, az1, an1;
            if (l == 0) {
                // input feature size is 1: Wi is [192][1]
                const float wr = Wi[j], wz = Wi[kH + j], wn = Wi[2 * kH + j];
                ar0 = wr * xv0; az0 = wz * xv0; an0 = wn * xv0;
                ar1 = wr * xv1; az1 = wz * xv1; an1 = wn * xv1;
            } else {
                ar0 = az0 = an0 = ar1 = az1 = an1 = 0.0f;
                const float* wrp = Wi + (size_t)j * kH;
                const float* wzp = Wi + (size_t)(kH + j) * kH;
                const float* wnp = Wi + (size_t)(2 * kH + j) * kH;
                #pragma unroll
                for (int k = 0; k < kH; ++k) {
                    const float wr = wrp[k], wz = wzp[k], wn = wnp[k];
                    ar0 = fmaf(wr, x0[k], ar0);
                    az0 = fmaf(wz, x0[k], az0);
                    an0 = fmaf(wn, x0[k], an0);
                    ar1 = fmaf(wr, x1[k], ar1);
                    az1 = fmaf(wz, x1[k], az1);
                    an1 = fmaf(wn, x1[k], an1);
                }
            }
            const float bir = bi[j], biz = bi[kH + j], bin = bi[2 * kH + j];
            const float bhr = bh[j], bhz = bh[kH + j], bhn = bh[2 * kH + j];
            // t = 0: h = 0 -> gh = bh
            const float r0 = sigm(ar0 + bir + bhr);
            const float z0 = sigm(az0 + biz + bhz);
            const float n0 = tanh_fast(an0 + bin + r0 * bhn);
            h0buf[j][lane]    = (1.0f - z0) * n0;
            i1buf[0][j][lane] = ar1 + bir;
            i1buf[1][j][lane] = az1 + biz;
            i1buf[2][j][lane] = an1 + bin;
        }
        __syncthreads();

        // full h(t=0) for my row -> next-layer x0 / phase-B operand
        #pragma unroll
        for (int k = 0; k < kH; ++k) x0[k] = h0buf[k][lane];

        // ---- phase B: t=1 ----
        #pragma unroll 1
        for (int jj = 0; jj < kJPT; ++jj) {
            const int j = jw * kJPT + jj;
            float hr = 0.0f, hz = 0.0f, hn = 0.0f;
            const float* wrp = Wh + (size_t)j * kH;
            const float* wzp = Wh + (size_t)(kH + j) * kH;
            const float* wnp = Wh + (size_t)(2 * kH + j) * kH;
            #pragma unroll
            for (int k = 0; k < kH; ++k) {
                hr = fmaf(wrp[k], x0[k], hr);
                hz = fmaf(wzp[k], x0[k], hz);
                hn = fmaf(wnp[k], x0[k], hn);
            }
            const float bhr = bh[j], bhz = bh[kH + j], bhn = bh[2 * kH + j];
            const float r1 = sigm(i1buf[0][j][lane] + hr + bhr);
            const float z1 = sigm(i1buf[1][j][lane] + hz + bhz);
            const float n1 = tanh_fast(i1buf[2][j][lane] + r1 * (hn + bhn));
            h1buf[j][lane] = (1.0f - z1) * n1 + z1 * h0buf[j][lane];
        }
        __syncthreads();

        #pragma unroll
        for (int k = 0; k < kH; ++k) x1[k] = h1buf[k][lane];
        // No barrier needed: next phase A writes h0buf/i1buf only, whose last
        // reads were before the barrier above; h1buf is next written after the
        // next phase-A barrier.
    }

    // Final linear. out[2*(row-B/2) + t] = Wf . h_t + bf
    if (jw == 0) {
        float a0 = bfp[0], a1 = bfp[0];
        #pragma unroll
        for (int k = 0; k < kH; ++k) {
            const float w = Wf[k];
            a0 = fmaf(w, x0[k], a0);
            a1 = fmaf(w, x1[k], a1);
        }
        const int ob = 2 * (grow - kB / 2);
        reinterpret_cast<float2*>(out)[ob >> 1] = make_float2(a0, a1);
    }
}

extern "C" void kernel_launch(void* const* d_in, const int* in_sizes, int n_in,
                              void* d_out, int out_size, void* d_ws, size_t ws_size,
                              hipStream_t stream) {
    const float* x    = (const float*)d_in[0];
    const float* Wih0 = (const float*)d_in[1];
    const float* Whh0 = (const float*)d_in[2];
    const float* bih0 = (const float*)d_in[3];
    const float* bhh0 = (const float*)d_in[4];
    const float* WihL = (const float*)d_in[5];
    const float* WhhL = (const float*)d_in[6];
    const float* bihL = (const float*)d_in[7];
    const float* bhhL = (const float*)d_in[8];
    const float* Wf   = (const float*)d_in[9];
    const float* bfp  = (const float*)d_in[10];

    dim3 grid(kRows / kRPB);   // 128 blocks
    dim3 block(kBlk);          // 512 threads

    gru_fused<<<grid, block, 0, stream>>>(x, Wih0, Whh0, bih0, bhh0,
                                          WihL, WhhL, bihL, bhhL,
                                          Wf, bfp, (float*)d_out);
}

// Round 2
// 3420.893 us; speedup vs baseline: 3.5301x; 3.5301x over previous
//
#include <hip/hip_runtime.h>

// Fused 64-layer GRU, H=64, T=2, B=16384; only batch rows 8192..16383 feed the
// output (reference's reshape(T,B,-1)[-1] picks out_flat rows B..2B-1, i.e.
// b = B/2 + b'//2, t = b'%2). Verified exact (absmax 0.0) in round 1.
//
// Round-2 structure (spill-free): 128 blocks x 512 threads. lane = batch row
// (64 rows/block), 8 waves split the 64 hidden outputs j (8 j per thread).
// Weight addresses are wave-uniform -> scalar loads. Layer input lives in LDS
// as [k][row] (stride-1 across lanes, conflict-free) and is streamed through
// 16-element register tiles; t=1 input gates + own-h0 stay in registers
// (same thread does phase A and B for the same j), so no i1 LDS buffer and
// no 64-float per-thread arrays -> no scratch.

namespace {

constexpr int kH    = 64;          // hidden size
constexpr int kL    = 64;          // layers
constexpr int kB    = 16384;       // batch
constexpr int kRPB  = 64;          // rows per block (= lanes)
constexpr int kJW   = 8;           // j-split waves per block
constexpr int kJPT  = kH / kJW;    // j per thread = 8
constexpr int kBlk  = kJW * 64;    // 512 threads
constexpr int kPad  = 65;          // LDS row-dim stride (dwords)
constexpr int kKT   = 16;          // k-tile held in registers

__device__ __forceinline__ float sigm(float v) {
    float e = __expf(-v);
    return __builtin_amdgcn_rcpf(1.0f + e);
}
// tanh(x) = (1 - e^-2x) / (1 + e^-2x); |x| bounded here.
__device__ __forceinline__ float tanh_fast(float v) {
    float e = __expf(-2.0f * v);
    return (1.0f - e) * __builtin_amdgcn_rcpf(1.0f + e);
}

} // namespace

extern "C" __global__ __launch_bounds__(kBlk, 2)
void gru_fused(const float* __restrict__ x,
               const float* __restrict__ Wih0, const float* __restrict__ Whh0,
               const float* __restrict__ bih0, const float* __restrict__ bhh0,
               const float* __restrict__ WihL, const float* __restrict__ WhhL,
               const float* __restrict__ bihL, const float* __restrict__ bhhL,
               const float* __restrict__ Wf,   const float* __restrict__ bfp,
               float* __restrict__ out)
{
    // [buf][k][row]; layer l reads buf (l&1), writes buf (l&1)^1.
    __shared__ float X0[2][kH][kPad];   // t=0 hidden chain
    __shared__ float X1[2][kH][kPad];   // t=1 hidden chain

    const int tid  = (int)threadIdx.x;
    const int lane = tid & 63;                                  // row in block
    const int jw   = __builtin_amdgcn_readfirstlane(tid >> 6);  // 0..7
    const int grow = kB / 2 + (int)blockIdx.x * kRPB + lane;    // global row

    const float xv0 = x[grow * 2 + 0];
    const float xv1 = x[grow * 2 + 1];

    float h0s[kJPT];                          // own t=0 hidden values
    float i1r[kJPT], i1z[kJPT], i1n[kJPT];    // own t=1 input gates (+bias)

    #pragma unroll 1
    for (int l = 0; l < kL; ++l) {
        const int rb = l & 1, wb = rb ^ 1;
        const float *Wi, *Wh, *bi, *bh;
        if (l == 0) { Wi = Wih0; Wh = Whh0; bi = bih0; bh = bhh0; }
        else {
            Wi = WihL + (size_t)(l - 1) * 3 * kH * kH;
            Wh = WhhL + (size_t)(l - 1) * 3 * kH * kH;
            bi = bihL + (size_t)(l - 1) * 3 * kH;
            bh = bhhL + (size_t)(l - 1) * 3 * kH;
        }

        // ---------------- phase A: input GEMM (t=0 & t=1) + t=0 gates ------
        float a0r[kJPT], a0z[kJPT], a0n[kJPT];
        float a1r[kJPT], a1z[kJPT], a1n[kJPT];

        if (l == 0) {
            // feature size 1: Wi is [192][1]
            #pragma unroll
            for (int jj = 0; jj < kJPT; ++jj) {
                const int j = jw * kJPT + jj;
                const float wr = Wi[j], wz = Wi[kH + j], wn = Wi[2 * kH + j];
                a0r[jj] = wr * xv0; a0z[jj] = wz * xv0; a0n[jj] = wn * xv0;
                a1r[jj] = wr * xv1; a1z[jj] = wz * xv1; a1n[jj] = wn * xv1;
            }
        } else {
            #pragma unroll
            for (int jj = 0; jj < kJPT; ++jj)
                a0r[jj] = a0z[jj] = a0n[jj] = a1r[jj] = a1z[jj] = a1n[jj] = 0.0f;
            #pragma unroll 1
            for (int kt = 0; kt < kH; kt += kKT) {
                float xa[kKT], xb[kKT];
                #pragma unroll
                for (int q = 0; q < kKT; ++q) {
                    xa[q] = X0[rb][kt + q][lane];
                    xb[q] = X1[rb][kt + q][lane];
                }
                #pragma unroll
                for (int jj = 0; jj < kJPT; ++jj) {
                    const int j = jw * kJPT + jj;
                    const float* wrp = Wi + (size_t)j * kH + kt;
                    const float* wzp = Wi + (size_t)(kH + j) * kH + kt;
                    const float* wnp = Wi + (size_t)(2 * kH + j) * kH + kt;
                    #pragma unroll
                    for (int q = 0; q < kKT; ++q) {
                        const float wr = wrp[q], wz = wzp[q], wn = wnp[q];
                        a0r[jj] = fmaf(wr, xa[q], a0r[jj]);
                        a1r[jj] = fmaf(wr, xb[q], a1r[jj]);
                        a0z[jj] = fmaf(wz, xa[q], a0z[jj]);
                        a1z[jj] = fmaf(wz, xb[q], a1z[jj]);
                        a0n[jj] = fmaf(wn, xa[q], a0n[jj]);
                        a1n[jj] = fmaf(wn, xb[q], a1n[jj]);
                    }
                }
            }
        }
        #pragma unroll
        for (int jj = 0; jj < kJPT; ++jj) {
            const int j = jw * kJPT + jj;
            const float bir = bi[j], biz = bi[kH + j], bin = bi[2 * kH + j];
            const float bhr = bh[j], bhz = bh[kH + j], bhn = bh[2 * kH + j];
            // t = 0: h_prev = 0 -> gh = bh
            const float r0 = sigm(a0r[jj] + bir + bhr);
            const float z0 = sigm(a0z[jj] + biz + bhz);
            const float n0 = tanh_fast(a0n[jj] + bin + r0 * bhn);
            const float h0 = (1.0f - z0) * n0;
            h0s[jj] = h0;
            X0[wb][j][lane] = h0;
            i1r[jj] = a1r[jj] + bir;
            i1z[jj] = a1z[jj] + biz;
            i1n[jj] = a1n[jj] + bin;
        }
        __syncthreads();

        // ---------------- phase B: hidden GEMM (t=1) + t=1 gates ------------
        float hr[kJPT], hz[kJPT], hn[kJPT];
        #pragma unroll
        for (int jj = 0; jj < kJPT; ++jj) hr[jj] = hz[jj] = hn[jj] = 0.0f;
        #pragma unroll 1
        for (int kt = 0; kt < kH; kt += kKT) {
            float xa[kKT];
            #pragma unroll
            for (int q = 0; q < kKT; ++q) xa[q] = X0[wb][kt + q][lane];
            #pragma unroll
            for (int jj = 0; jj < kJPT; ++jj) {
                const int j = jw * kJPT + jj;
                const float* wrp = Wh + (size_t)j * kH + kt;
                const float* wzp = Wh + (size_t)(kH + j) * kH + kt;
                const float* wnp = Wh + (size_t)(2 * kH + j) * kH + kt;
                #pragma unroll
                for (int q = 0; q < kKT; ++q) {
                    hr[jj] = fmaf(wrp[q], xa[q], hr[jj]);
                    hz[jj] = fmaf(wzp[q], xa[q], hz[jj]);
                    hn[jj] = fmaf(wnp[q], xa[q], hn[jj]);
                }
            }
        }
        #pragma unroll
        for (int jj = 0; jj < kJPT; ++jj) {
            const int j = jw * kJPT + jj;
            const float bhr = bh[j], bhz = bh[kH + j], bhn = bh[2 * kH + j];
            const float r1 = sigm(i1r[jj] + hr[jj] + bhr);
            const float z1 = sigm(i1z[jj] + hz[jj] + bhz);
            const float n1 = tanh_fast(i1n[jj] + r1 * (hn[jj] + bhn));
            X1[wb][j][lane] = (1.0f - z1) * n1 + z1 * h0s[jj];
        }
        __syncthreads();
    }

    // Final linear; last layer (l=63) wrote buffers [0].
    if (jw == 0) {
        float a0 = bfp[0], a1 = bfp[0];
        #pragma unroll
        for (int k = 0; k < kH; ++k) {
            const float w = Wf[k];
            a0 = fmaf(w, X0[0][k][lane], a0);
            a1 = fmaf(w, X1[0][k][lane], a1);
        }
        const int ob = 2 * (grow - kB / 2);
        reinterpret_cast<float2*>(out)[ob >> 1] = make_float2(a0, a1);
    }
}

extern "C" void kernel_launch(void* const* d_in, const int* in_sizes, int n_in,
                              void* d_out, int out_size, void* d_ws, size_t ws_size,
                              hipStream_t stream) {
    const float* x    = (const float*)d_in[0];
    const float* Wih0 = (const float*)d_in[1];
    const float* Whh0 = (const float*)d_in[2];
    const float* bih0 = (const float*)d_in[3];
    const float* bhh0 = (const float*)d_in[4];
    const float* WihL = (const float*)d_in[5];
    const float* WhhL = (const float*)d_in[6];
    const float* bihL = (const float*)d_in[7];
    const float* bhhL = (const float*)d_in[8];
    const float* Wf   = (const float*)d_in[9];
    const float* bfp  = (const float*)d_in[10];

    dim3 grid(kB / 2 / kRPB);  // 128 blocks
    dim3 block(kBlk);          // 512 threads

    gru_fused<<<grid, block, 0, stream>>>(x, Wih0, Whh0, bih0, bhh0,
                                          WihL, WhhL, bihL, bhhL,
                                          Wf, bfp, (float*)d_out);
}

// Round 3
// 448.724 us; speedup vs baseline: 26.9121x; 7.6236x over previous
//
#include <hip/hip_runtime.h>

// Fused 64-layer GRU (H=64, T=2, B=16384) -- MFMA split-bf16 version.
// Only batch rows 8192..16383 feed the output (verified exact in rounds 1-2).
//
// Grid: 256 blocks x 512 threads (8 waves), 32 batch rows per block -> all 256
// CUs engaged. Per layer, per block:
//   phase A: input GEMM, A=[64 (2t x 32rows)]x[64k], W'=[192n]x[64k] via
//            mfma_f32_16x16x32_bf16 with split-bf16 (hi/lo; 3 products);
//            t0-waves compute t=0 gates -> h0 (X LDS + H0f fp32),
//            t1-waves store t=1 input gates (fp32 I1).
//   phase B: hidden GEMM A=h0[32]x[64], then t=1 gates -> h1.
// Weight N-dim reordered (n = jq*48 + g*16 + jc) by a prep kernel into d_ws as
// split-bf16 so each wave's lanes hold r,z,n gates for its 16 j in-register.
// Gates/biases/I1/z*h0 all fp32; only GEMM operands are split-bf16 (~2^-16).

typedef __attribute__((ext_vector_type(8))) short short8;
typedef __attribute__((ext_vector_type(4))) float f32x4;

#define MFMA16(a, b, c) __builtin_amdgcn_mfma_f32_16x16x32_bf16((a), (b), (c), 0, 0, 0)

namespace {

constexpr int kH    = 64;
constexpr int kL    = 64;
constexpr int kB    = 16384;
constexpr int kRPB  = 32;                 // rows per block
constexpr int kGrid = (kB / 2) / kRPB;    // 256 blocks
constexpr int kBlk  = 512;                // 8 waves
constexpr int kXP   = 72;                 // X pad (shorts; 144 B row stride, 16B-aligned)
constexpr int kI1P  = 194;                // I1 pad (f32)
constexpr int kH0P  = 66;                 // H0f pad (f32)

// d_ws layout: shorts region then float region.
constexpr size_t nWi      = (size_t)63 * 192 * 64;   // Wih layers 1..63 (idx l-1)
constexpr size_t nWh      = (size_t)64 * 192 * 64;   // Whh layers 0..63
constexpr size_t oWiHi    = 0;
constexpr size_t oWiLo    = oWiHi + nWi;
constexpr size_t oWhHi    = oWiLo + nWi;
constexpr size_t oWhLo    = oWhHi + nWh;
constexpr size_t oShortEnd= oWhLo + nWh;             // 3,121,152 shorts
constexpr size_t nB1      = (size_t)64 * 192;
constexpr size_t oBi      = 0;                       // floats, after short region
constexpr size_t oBh      = nB1;

__device__ __forceinline__ unsigned short rne_bf16(float f) {
    unsigned u = __float_as_uint(f);
    return (unsigned short)((u + 0x7FFFu + ((u >> 16) & 1u)) >> 16);
}
__device__ __forceinline__ float bf2f(unsigned short s) {
    return __uint_as_float(((unsigned)s) << 16);
}
__device__ __forceinline__ float sigm(float v) {
    float e = __expf(-v);
    return __builtin_amdgcn_rcpf(1.0f + e);
}
__device__ __forceinline__ float tanh_fast(float v) {
    float e = __expf(-2.0f * v);
    return (1.0f - e) * __builtin_amdgcn_rcpf(1.0f + e);
}

} // namespace

// ---------------------------------------------------------------------------
// Prep: fp32 weights -> reordered split-bf16 in ws; biases reordered fp32.
// n-reorder: n = jq*48 + g*16 + jc  <->  orig row = g*64 + jq*16 + jc.
extern "C" __global__ void gru_prep(const float* __restrict__ Whh0,
                                    const float* __restrict__ bih0,
                                    const float* __restrict__ bhh0,
                                    const float* __restrict__ WihL,
                                    const float* __restrict__ WhhL,
                                    const float* __restrict__ bihL,
                                    const float* __restrict__ bhhL,
                                    short* __restrict__ wsS,
                                    float* __restrict__ wsF)
{
    int idx = (int)blockIdx.x * 256 + (int)threadIdx.x;
    const int nWiT = 63 * 192 * 64;
    const int nWhT = 64 * 192 * 64;
    const int nBT  = 64 * 192;

    if (idx < nWiT) {
        const int li  = idx / (192 * 64);           // ref layer li+1
        const int rem = idx % (192 * 64);
        const int n = rem / 64, k = rem % 64;
        const int jq = n / 48, g = (n % 48) / 16, jc = n % 16;
        const int row = g * 64 + jq * 16 + jc;
        const float w = WihL[(size_t)li * 192 * 64 + row * 64 + k];
        const unsigned short hi = rne_bf16(w);
        wsS[oWiHi + idx] = (short)hi;
        wsS[oWiLo + idx] = (short)rne_bf16(w - bf2f(hi));
        return;
    }
    idx -= nWiT;
    if (idx < nWhT) {
        const int li  = idx / (192 * 64);
        const int rem = idx % (192 * 64);
        const int n = rem / 64, k = rem % 64;
        const int jq = n / 48, g = (n % 48) / 16, jc = n % 16;
        const int row = g * 64 + jq * 16 + jc;
        const float w = (li == 0) ? Whh0[row * 64 + k]
                                  : WhhL[(size_t)(li - 1) * 192 * 64 + row * 64 + k];
        const unsigned short hi = rne_bf16(w);
        wsS[oWhHi + idx] = (short)hi;
        wsS[oWhLo + idx] = (short)rne_bf16(w - bf2f(hi));
        return;
    }
    idx -= nWhT;
    if (idx < nBT) {
        const int li = idx / 192, n = idx % 192;
        const int jq = n / 48, g = (n % 48) / 16, jc = n % 16;
        const int row = g * 64 + jq * 16 + jc;
        wsF[oBi + idx] = (li == 0) ? bih0[row] : bihL[(size_t)(li - 1) * 192 + row];
        return;
    }
    idx -= nBT;
    if (idx < nBT) {
        const int li = idx / 192, n = idx % 192;
        const int jq = n / 48, g = (n % 48) / 16, jc = n % 16;
        const int row = g * 64 + jq * 16 + jc;
        wsF[oBh + idx] = (li == 0) ? bhh0[row] : bhhL[(size_t)(li - 1) * 192 + row];
        return;
    }
}

// ---------------------------------------------------------------------------
extern "C" __global__ __launch_bounds__(kBlk, 2)
void gru_mfma(const float* __restrict__ x,
              const float* __restrict__ Wih0,
              const float* __restrict__ Wf,
              const float* __restrict__ bfp,
              const short* __restrict__ wsS,
              const float* __restrict__ wsF,
              float* __restrict__ out)
{
    __shared__ short Xhi[2][2 * kRPB][kXP];   // [buf][(t,row)][k] 18 KiB
    __shared__ short Xlo[2][2 * kRPB][kXP];   // 18 KiB
    __shared__ float H0f[kRPB][kH0P];         // exact h0 for z*h0 (8.25 KiB)
    __shared__ float I1[kRPB][kI1P];          // t=1 input gates, fp32 (24.25 KiB)

    const int tid  = (int)threadIdx.x;
    const int lane = tid & 63;
    const int l15  = lane & 15;
    const int l4   = lane >> 4;                                  // 0..3
    const int jw   = __builtin_amdgcn_readfirstlane(tid >> 6);   // wave 0..7
    const int jg   = jw & 3;                                     // j-group
    const int mg   = jw >> 2;                                    // 0:t0-rows 1:t1-rows
    const int rowbase = kB / 2 + (int)blockIdx.x * kRPB;

    const int n0    = jg * 48 + l15;           // n index for gate 0
    const int jcol  = jg * 16 + l15;           // hidden-unit index
    const int koff  = l4 * 8;                  // k sub-offset within frag
    const int wfbase = n0 * 64 + koff;         // weight frag offset (+g*1024 +ks*32)

    short8 wiHi[3][2], wiLo[3][2];             // prefetched Wi frags (layer l)

    #pragma unroll 1
    for (int l = 0; l < kL; ++l) {
        const int rb = l & 1, wb = rb ^ 1;

        // -------- phase A: input GEMM --------
        f32x4 acc[2][3];
        #pragma unroll
        for (int mt = 0; mt < 2; ++mt)
            #pragma unroll
            for (int g = 0; g < 3; ++g)
                acc[mt][g] = f32x4{0.f, 0.f, 0.f, 0.f};

        if (l == 0) {
            // F = 1: direct scalar product, no MFMA.
            float wv[3];
            #pragma unroll
            for (int g = 0; g < 3; ++g) wv[g] = Wih0[g * 64 + jg * 16 + l15];
            #pragma unroll
            for (int mt = 0; mt < 2; ++mt)
                #pragma unroll
                for (int r = 0; r < 4; ++r) {
                    const int trow = mg * 32 + mt * 16 + l4 * 4 + r;
                    const float xv = x[(rowbase + (trow & 31)) * 2 + (trow >> 5)];
                    #pragma unroll
                    for (int g = 0; g < 3; ++g) acc[mt][g][r] = wv[g] * xv;
                }
        } else {
            short8 ahi[2][2], alo[2][2];
            #pragma unroll
            for (int mt = 0; mt < 2; ++mt)
                #pragma unroll
                for (int ks = 0; ks < 2; ++ks) {
                    const int arow = mg * 32 + mt * 16 + l15;
                    ahi[mt][ks] = *reinterpret_cast<const short8*>(&Xhi[rb][arow][ks * 32 + koff]);
                    alo[mt][ks] = *reinterpret_cast<const short8*>(&Xlo[rb][arow][ks * 32 + koff]);
                }
            #pragma unroll
            for (int mt = 0; mt < 2; ++mt)
                #pragma unroll
                for (int g = 0; g < 3; ++g)
                    #pragma unroll
                    for (int ks = 0; ks < 2; ++ks) {
                        acc[mt][g] = MFMA16(ahi[mt][ks], wiHi[g][ks], acc[mt][g]);
                        acc[mt][g] = MFMA16(ahi[mt][ks], wiLo[g][ks], acc[mt][g]);
                        acc[mt][g] = MFMA16(alo[mt][ks], wiHi[g][ks], acc[mt][g]);
                    }
        }

        // Prefetch Whh frags (consumed in phase B; latency hides under epilogue A).
        short8 whHi[3][2], whLo[3][2];
        {
            const short* bh_ = wsS + oWhHi + (size_t)l * 192 * 64;
            const short* bl_ = wsS + oWhLo + (size_t)l * 192 * 64;
            #pragma unroll
            for (int g = 0; g < 3; ++g)
                #pragma unroll
                for (int ks = 0; ks < 2; ++ks) {
                    const int off = wfbase + g * 1024 + ks * 32;
                    whHi[g][ks] = *reinterpret_cast<const short8*>(bh_ + off);
                    whLo[g][ks] = *reinterpret_cast<const short8*>(bl_ + off);
                }
        }

        // Biases (reordered) for this layer.
        const float* biL = wsF + oBi + (size_t)l * 192;
        const float* bhL = wsF + oBh + (size_t)l * 192;
        float bi_[3], bh_[3];
        #pragma unroll
        for (int g = 0; g < 3; ++g) { bi_[g] = biL[n0 + g * 16]; bh_[g] = bhL[n0 + g * 16]; }

        // -------- epilogue A --------
        if (mg == 0) {
            // t=0 gates (h_prev = 0 -> gh = bh) -> h0
            #pragma unroll
            for (int mt = 0; mt < 2; ++mt)
                #pragma unroll
                for (int r = 0; r < 4; ++r) {
                    const int trow = mt * 16 + l4 * 4 + r;         // 0..31
                    const float r0 = sigm(acc[mt][0][r] + bi_[0] + bh_[0]);
                    const float z0 = sigm(acc[mt][1][r] + bi_[1] + bh_[1]);
                    const float n0v = tanh_fast(acc[mt][2][r] + bi_[2] + r0 * bh_[2]);
                    const float h0 = (1.0f - z0) * n0v;
                    H0f[trow][jcol] = h0;
                    const unsigned short h = rne_bf16(h0);
                    Xhi[wb][trow][jcol] = (short)h;
                    Xlo[wb][trow][jcol] = (short)rne_bf16(h0 - bf2f(h));
                }
        } else {
            // t=1 input gates (+bi) -> I1 (fp32 carry to phase B)
            #pragma unroll
            for (int mt = 0; mt < 2; ++mt)
                #pragma unroll
                for (int r = 0; r < 4; ++r) {
                    const int trow = mt * 16 + l4 * 4 + r;         // 0..31
                    I1[trow][n0]      = acc[mt][0][r] + bi_[0];
                    I1[trow][n0 + 16] = acc[mt][1][r] + bi_[1];
                    I1[trow][n0 + 32] = acc[mt][2][r] + bi_[2];
                }
        }
        __syncthreads();

        // -------- phase B: hidden GEMM (t=1), A = h0 rows [0,32) --------
        f32x4 acc2[3];
        #pragma unroll
        for (int g = 0; g < 3; ++g) acc2[g] = f32x4{0.f, 0.f, 0.f, 0.f};
        {
            short8 hhi[2], hlo[2];
            #pragma unroll
            for (int ks = 0; ks < 2; ++ks) {
                const int hrow = mg * 16 + l15;                    // wave's M-tile = mg
                hhi[ks] = *reinterpret_cast<const short8*>(&Xhi[wb][hrow][ks * 32 + koff]);
                hlo[ks] = *reinterpret_cast<const short8*>(&Xlo[wb][hrow][ks * 32 + koff]);
            }
            #pragma unroll
            for (int g = 0; g < 3; ++g)
                #pragma unroll
                for (int ks = 0; ks < 2; ++ks) {
                    acc2[g] = MFMA16(hhi[ks], whHi[g][ks], acc2[g]);
                    acc2[g] = MFMA16(hhi[ks], whLo[g][ks], acc2[g]);
                    acc2[g] = MFMA16(hlo[ks], whHi[g][ks], acc2[g]);
                }
        }

        // Prefetch next layer's Wi frags (layer l+1 -> ws index l).
        if (l < kL - 1) {
            const short* bh_ = wsS + oWiHi + (size_t)l * 192 * 64;
            const short* bl_ = wsS + oWiLo + (size_t)l * 192 * 64;
            #pragma unroll
            for (int g = 0; g < 3; ++g)
                #pragma unroll
                for (int ks = 0; ks < 2; ++ks) {
                    const int off = wfbase + g * 1024 + ks * 32;
                    wiHi[g][ks] = *reinterpret_cast<const short8*>(bh_ + off);
                    wiLo[g][ks] = *reinterpret_cast<const short8*>(bl_ + off);
                }
        }

        // -------- epilogue B: t=1 gates -> h1 --------
        #pragma unroll
        for (int r = 0; r < 4; ++r) {
            const int row = mg * 16 + l4 * 4 + r;                  // 0..31
            const float hr = acc2[0][r] + bh_[0];
            const float hz = acc2[1][r] + bh_[1];
            const float hn = acc2[2][r] + bh_[2];
            const float r1 = sigm(I1[row][n0] + hr);
            const float z1 = sigm(I1[row][n0 + 16] + hz);
            const float n1v = tanh_fast(I1[row][n0 + 32] + r1 * hn);
            const float h1 = (1.0f - z1) * n1v + z1 * H0f[row][jcol];
            const unsigned short h = rne_bf16(h1);
            Xhi[wb][32 + row][jcol] = (short)h;
            Xlo[wb][32 + row][jcol] = (short)rne_bf16(h1 - bf2f(h));
        }
        __syncthreads();
    }

    // -------- final linear: out[2*(bid*32+row)+t] = Wf . h + bf --------
    // Layer 63 wrote buffer 0. lane = (t,row): t = lane>>5, row = lane&31.
    if (jw == 0) {
        float a = 0.0f;
        #pragma unroll
        for (int k = 0; k < kH; ++k) {
            const float hv = bf2f((unsigned short)Xhi[0][lane][k]) +
                             bf2f((unsigned short)Xlo[0][lane][k]);
            a = fmaf(Wf[k], hv, a);
        }
        out[2 * ((int)blockIdx.x * kRPB + (lane & 31)) + (lane >> 5)] = a + bfp[0];
    }
}

// ---------------------------------------------------------------------------
extern "C" void kernel_launch(void* const* d_in, const int* in_sizes, int n_in,
                              void* d_out, int out_size, void* d_ws, size_t ws_size,
                              hipStream_t stream) {
    const float* x    = (const float*)d_in[0];
    const float* Wih0 = (const float*)d_in[1];
    const float* Whh0 = (const float*)d_in[2];
    const float* bih0 = (const float*)d_in[3];
    const float* bhh0 = (const float*)d_in[4];
    const float* WihL = (const float*)d_in[5];
    const float* WhhL = (const float*)d_in[6];
    const float* bihL = (const float*)d_in[7];
    const float* bhhL = (const float*)d_in[8];
    const float* Wf   = (const float*)d_in[9];
    const float* bfp  = (const float*)d_in[10];

    short* wsS = (short*)d_ws;
    float* wsF = (float*)((char*)d_ws + oShortEnd * sizeof(short));

    // prep: 774144 + 786432 + 2*12288 = 1,585,152 elements
    const int prepThreads = 1585152;
    gru_prep<<<dim3(prepThreads / 256), dim3(256), 0, stream>>>(
        Whh0, bih0, bhh0, WihL, WhhL, bihL, bhhL, wsS, wsF);

    gru_mfma<<<dim3(kGrid), dim3(kBlk), 0, stream>>>(
        x, Wih0, Wf, bfp, wsS, wsF, (float*)d_out);
}